// Round 1
// baseline (486.247 us; speedup 1.0000x reference)
//
#include <hip/hip_runtime.h>
#include <hip/hip_bf16.h>

#define Tn 4096
#define Cn 768
#define Hn 12
#define DHn 64
#define BAND 192
#define BR 16
#define TJ (BAND + BR)   // 208 staged K/V rows per block

typedef __attribute__((ext_vector_type(8))) short short8;
typedef __attribute__((ext_vector_type(4))) short short4v;
typedef __attribute__((ext_vector_type(4))) float f32x4;

__device__ __forceinline__ float b2f(unsigned short u) {
  union { unsigned int i; float f; } z; z.i = ((unsigned int)u) << 16; return z.f;
}
__device__ __forceinline__ unsigned short f2b(float f) {
  union { float f; unsigned int i; } z; z.f = f;
  unsigned int r = z.i + 0x7FFFu + ((z.i >> 16) & 1u);
  return (unsigned short)(r >> 16);
}

// ---------------- f32 -> bf16 convert (vectorized) ----------------
__global__ __launch_bounds__(256) void k_f32_to_bf16(const float* __restrict__ in,
                                                     unsigned short* __restrict__ out, int n4) {
  int idx = blockIdx.x * 256 + threadIdx.x;
  int stride = gridDim.x * 256;
  for (int i = idx; i < n4; i += stride) {
    float4 v = ((const float4*)in)[i];
    short4v o;
    o.x = (short)f2b(v.x); o.y = (short)f2b(v.y);
    o.z = (short)f2b(v.z); o.w = (short)f2b(v.w);
    ((short4v*)out)[i] = o;
  }
}

// ---------------- W[K][N] f32 -> WT[N][K] bf16 (tiled transpose) ----------------
__global__ __launch_bounds__(256) void k_transpose_bf16(const float* __restrict__ W,
                                                        unsigned short* __restrict__ WT,
                                                        int K, int N) {
  __shared__ float tile[32][33];
  int n0 = blockIdx.x * 32, k0 = blockIdx.y * 32;
  int tx = threadIdx.x, ty = threadIdx.y; // 32 x 8
  for (int r = ty; r < 32; r += 8) tile[r][tx] = W[(size_t)(k0 + r) * N + n0 + tx];
  __syncthreads();
  for (int r = ty; r < 32; r += 8) WT[(size_t)(n0 + r) * K + k0 + tx] = f2b(tile[tx][r]);
}

// ---------------- bf16 MFMA GEMM: C[M,N] = A[M,K] * BT[N,K]^T ----------------
// 128x128 tile, BK=32, 4 waves (2x2), 4x4 fragments of 16x16x32 per wave.
// EPI==0: bf16 output; EPI==1: f32 output.
template<int EPI>
__global__ __launch_bounds__(256) void k_gemm_bt(const unsigned short* __restrict__ A,
                                                 const unsigned short* __restrict__ BT,
                                                 void* __restrict__ Cout,
                                                 int M, int N, int K) {
  __shared__ unsigned short As[128 * 32];
  __shared__ unsigned short Bs[128 * 32];
  int tid = threadIdx.x, lane = tid & 63, wave = tid >> 6;
  int wr = wave >> 1, wc = wave & 1;
  int m0 = blockIdx.y * 128, n0 = blockIdx.x * 128;
  f32x4 acc[4][4] = {};
  const unsigned short* Ab = A + (size_t)m0 * K;
  const unsigned short* Bb = BT + (size_t)n0 * K;
  int arow = (lane >> 2), acol = (lane & 3) * 8;
  for (int k0 = 0; k0 < K; k0 += 32) {
    __syncthreads();
#pragma unroll
    for (int u = 0; u < 2; ++u) {
      int s = wave * 2 + u;                       // 0..7: 16 rows each
      const unsigned short* ga = Ab + (size_t)(s * 16 + arow) * K + k0 + acol;
      const unsigned short* gb = Bb + (size_t)(s * 16 + arow) * K + k0 + acol;
      __builtin_amdgcn_global_load_lds((const __attribute__((address_space(1))) void*)ga,
                                       (__attribute__((address_space(3))) void*)(As + s * 512),
                                       16, 0, 0);
      __builtin_amdgcn_global_load_lds((const __attribute__((address_space(1))) void*)gb,
                                       (__attribute__((address_space(3))) void*)(Bs + s * 512),
                                       16, 0, 0);
    }
    __syncthreads();
    short8 a[4], b[4];
#pragma unroll
    for (int m = 0; m < 4; ++m)
      a[m] = *(const short8*)(As + (wr * 64 + m * 16 + (lane & 15)) * 32 + (lane >> 4) * 8);
#pragma unroll
    for (int n = 0; n < 4; ++n)
      b[n] = *(const short8*)(Bs + (wc * 64 + n * 16 + (lane & 15)) * 32 + (lane >> 4) * 8);
#pragma unroll
    for (int m = 0; m < 4; ++m)
#pragma unroll
      for (int n = 0; n < 4; ++n)
        acc[m][n] = __builtin_amdgcn_mfma_f32_16x16x32_bf16(a[m], b[n], acc[m][n], 0, 0, 0);
  }
  int r0 = m0 + wr * 64 + (lane >> 4) * 4;
  int c0 = n0 + wc * 64 + (lane & 15);
#pragma unroll
  for (int m = 0; m < 4; ++m)
#pragma unroll
    for (int n = 0; n < 4; ++n)
#pragma unroll
      for (int i = 0; i < 4; ++i) {
        int row = r0 + m * 16 + i, col = c0 + n * 16;
        if (EPI == 0) ((unsigned short*)Cout)[(size_t)row * N + col] = f2b(acc[m][n][i]);
        else          ((float*)Cout)[(size_t)row * N + col] = acc[m][n][i];
      }
}

// ---------------- RoPE + split heads; qkv[T][3C] bf16 -> q_r/k_r/v [H][T][64] bf16 ----------------
__global__ __launch_bounds__(256) void k_rope_split(const unsigned short* __restrict__ qkv,
                                                    const float* __restrict__ cosT,
                                                    const float* __restrict__ sinT,
                                                    unsigned short* __restrict__ qr,
                                                    unsigned short* __restrict__ kr,
                                                    unsigned short* __restrict__ vs) {
  int unit = blockIdx.x * 4 + (threadIdx.x >> 6);  // over T*H
  int lane = threadIdx.x & 63;
  int t = unit / Hn, h = unit % Hn;
  size_t base = (size_t)t * (3 * Cn);
  float cv = cosT[t * DHn + lane], sv = sinT[t * DHn + lane];
  float qv = b2f(qkv[base + h * DHn + lane]);
  float kv = b2f(qkv[base + Cn + h * DHn + lane]);
  unsigned short vv = qkv[base + 2 * Cn + h * DHn + lane];
  float sgn = (lane < 32) ? -1.f : 1.f;            // rotate_half: [:d]=-x[d:], [d:]=x[:d]
  float qp = __shfl_xor(qv, 32);
  float kp = __shfl_xor(kv, 32);
  float qo = qv * cv + sgn * qp * sv;
  float ko = kv * cv + sgn * kp * sv;
  size_t o = ((size_t)h * Tn + t) * DHn + lane;
  qr[o] = f2b(qo); kr[o] = f2b(ko); vs[o] = vv;
}

// ---------------- banded causal attention pass ----------------
// PASS==0: out = P @ vin            (writes [H][T][64] bf16)
// PASS==1: out = y[T][C] = w0*v0 + w1*pv1 + w2*(P @ vin)
template<int PASS>
__global__ __launch_bounds__(256) void k_attn(const unsigned short* __restrict__ qr,
                                              const unsigned short* __restrict__ kr,
                                              const unsigned short* __restrict__ vin,
                                              const unsigned short* __restrict__ v0,
                                              const unsigned short* __restrict__ pv1g,
                                              unsigned short* __restrict__ outp,
                                              const float* __restrict__ dt_logit_p,
                                              const float* __restrict__ kap_p,
                                              const float* __restrict__ xi_p) {
  __shared__ __align__(16) unsigned short Ks[TJ * DHn];  // XOR-swizzled 16B units
  __shared__ __align__(16) unsigned short Vs[TJ * DHn];  // linear
  __shared__ __align__(16) float Ps[4][BAND];
  __shared__ __align__(16) float Qs[BR * DHn];
  int tid = threadIdx.x, lane = tid & 63, wave = tid >> 6;
  int i0 = blockIdx.x * BR;
  int h = blockIdx.y;
  int jt0 = i0 - BAND;
  float kap = log1pf(__expf(*kap_p));
  float xi  = log1pf(__expf(*xi_p));
  float pcoef = kap / (xi * xi);
  const size_t headoff = (size_t)h * Tn * DHn;

  // stage K (swizzled) and V (linear); zero-fill j<0
  for (int c = tid; c < TJ * 8; c += 256) {
    int jrr = c >> 3, c8 = c & 7;
    int j = jt0 + jrr;
    short8 kvv = {0, 0, 0, 0, 0, 0, 0, 0}, vvv = {0, 0, 0, 0, 0, 0, 0, 0};
    if (j >= 0) {
      kvv = *(const short8*)(kr + headoff + (size_t)j * DHn + c8 * 8);
      vvv = *(const short8*)(vin + headoff + (size_t)j * DHn + c8 * 8);
    }
    *(short8*)((char*)Ks + jrr * 128 + ((c8 ^ (jrr & 7)) << 4)) = kvv;
    *(short8*)((char*)Vs + jrr * 128 + (c8 << 4)) = vvv;
  }
  // stage Q rows as f32
  for (int e = tid; e < BR * DHn; e += 256) {
    int r = e >> 6, d = e & 63;
    Qs[e] = b2f(qr[headoff + (size_t)(i0 + r) * DHn + d]);
  }
  __syncthreads();

  float w0 = 0.f, w1 = 0.f, w2 = 0.f;
  if (PASS == 1) {
    float dt = 1.f / (1.f + __expf(-*dt_logit_p));
    float a0 = 1.f, a1 = dt, a2 = 0.5f * dt * dt;  // exp(-dt) cancels in normalization
    float inv = 1.f / (a0 + a1 + a2);
    w0 = a0 * inv; w1 = a1 * inv; w2 = a2 * inv;
  }

  for (int rr = 0; rr < BR / 4; ++rr) {
    int rl = (wave << 2) + rr;
    int i = i0 + rl;
    int jlo = i - (BAND - 1); if (jlo < 0) jlo = 0;
    int jcount = i - jlo + 1;          // <= BAND, uniform per wave-iteration
    int jbase = jlo - jt0;
    f32x4 qv[16];
#pragma unroll
    for (int z = 0; z < 16; ++z) qv[z] = *(const f32x4*)(Qs + rl * 64 + z * 4);

    float lg[3];
#pragma unroll
    for (int cc = 0; cc < 3; ++cc) {
      int jj = cc * 64 + lane;
      bool valid = jj < jcount;
      int jrr = valid ? (jbase + jj) : 0;
      const char* kb = (const char*)Ks + jrr * 128;
      int sw = (jrr & 7) << 4;
      float dot = 0.f;
#pragma unroll
      for (int c8 = 0; c8 < 8; ++c8) {
        short8 kvv = *(const short8*)(kb + ((c8 << 4) ^ sw));
        f32x4 qa = qv[c8 * 2], qb = qv[c8 * 2 + 1];
        dot += qa[0] * b2f((unsigned short)kvv[0]) + qa[1] * b2f((unsigned short)kvv[1])
             + qa[2] * b2f((unsigned short)kvv[2]) + qa[3] * b2f((unsigned short)kvv[3])
             + qb[0] * b2f((unsigned short)kvv[4]) + qb[1] * b2f((unsigned short)kvv[5])
             + qb[2] * b2f((unsigned short)kvv[6]) + qb[3] * b2f((unsigned short)kvv[7]);
      }
      float dist = (float)(i - (jlo + jj));
      float logit = 0.125f * dot - pcoef * dist * dist;
      lg[cc] = valid ? logit : -3.0e38f;
    }
    float mx = fmaxf(fmaxf(lg[0], lg[1]), lg[2]);
#pragma unroll
    for (int s = 32; s; s >>= 1) mx = fmaxf(mx, __shfl_xor(mx, s));
    float p[3], psum = 0.f;
#pragma unroll
    for (int cc = 0; cc < 3; ++cc) { p[cc] = __expf(lg[cc] - mx); psum += p[cc]; }
#pragma unroll
    for (int s = 32; s; s >>= 1) psum += __shfl_xor(psum, s);
    float inv_s = 1.f / psum;
#pragma unroll
    for (int cc = 0; cc < 3; ++cc) Ps[wave][cc * 64 + lane] = p[cc];
    __syncthreads();

    // PV: lane = d, serial over band
    float acc0 = 0.f, acc1 = 0.f;
    const unsigned short* vb = Vs + (size_t)jbase * 64 + lane;
    const float* pw = Ps[wave];
    int jj = 0;
    for (; jj + 1 < jcount; jj += 2) {
      acc0 = fmaf(pw[jj],     b2f(vb[(size_t)jj * 64]),       acc0);
      acc1 = fmaf(pw[jj + 1], b2f(vb[(size_t)(jj + 1) * 64]), acc1);
    }
    if (jj < jcount) acc0 = fmaf(pw[jj], b2f(vb[(size_t)jj * 64]), acc0);
    float res = (acc0 + acc1) * inv_s;

    size_t oidx = headoff + (size_t)i * DHn + lane;
    if (PASS == 0) {
      outp[oidx] = f2b(res);
    } else {
      float vvv = b2f(v0[oidx]);
      float p1v = b2f(pv1g[oidx]);
      float yv = w0 * vvv + w1 * p1v + w2 * res;
      outp[(size_t)i * Cn + h * DHn + lane] = f2b(yv);
    }
    __syncthreads();
  }
}

extern "C" void kernel_launch(void* const* d_in, const int* in_sizes, int n_in,
                              void* d_out, int out_size, void* d_ws, size_t ws_size,
                              hipStream_t stream) {
  (void)in_sizes; (void)n_in; (void)out_size; (void)ws_size;
  const float* x     = (const float*)d_in[0];
  const float* cosT  = (const float*)d_in[1];
  const float* sinT  = (const float*)d_in[2];
  const float* Wqkv  = (const float*)d_in[3];
  const float* Wproj = (const float*)d_in[4];
  const float* dtl   = (const float*)d_in[5];
  const float* kap   = (const float*)d_in[6];
  const float* xiu   = (const float*)d_in[7];
  float* out = (float*)d_out;
  char* ws = (char*)d_ws;
  size_t off = 0;
  auto alloc = [&](size_t bytes) { char* p = ws + off; off += (bytes + 255) & ~(size_t)255; return p; };
  unsigned short* x_bf   = (unsigned short*)alloc((size_t)Tn * Cn * 2);
  unsigned short* WqkvT  = (unsigned short*)alloc((size_t)3 * Cn * Cn * 2);
  unsigned short* WprojT = (unsigned short*)alloc((size_t)Cn * Cn * 2);
  unsigned short* qkv_bf = (unsigned short*)alloc((size_t)Tn * 3 * Cn * 2);
  unsigned short* q_r    = (unsigned short*)alloc((size_t)Hn * Tn * DHn * 2);
  unsigned short* k_r    = (unsigned short*)alloc((size_t)Hn * Tn * DHn * 2);
  unsigned short* v_s    = (unsigned short*)alloc((size_t)Hn * Tn * DHn * 2);
  unsigned short* pv1    = (unsigned short*)alloc((size_t)Hn * Tn * DHn * 2);
  unsigned short* y_bf   = (unsigned short*)alloc((size_t)Tn * Cn * 2);

  k_f32_to_bf16<<<512, 256, 0, stream>>>(x, x_bf, Tn * Cn / 4);
  k_transpose_bf16<<<dim3(3 * Cn / 32, Cn / 32), dim3(32, 8), 0, stream>>>(Wqkv, WqkvT, Cn, 3 * Cn);
  k_transpose_bf16<<<dim3(Cn / 32, Cn / 32), dim3(32, 8), 0, stream>>>(Wproj, WprojT, Cn, Cn);
  k_gemm_bt<0><<<dim3(3 * Cn / 128, Tn / 128), 256, 0, stream>>>(x_bf, WqkvT, qkv_bf, Tn, 3 * Cn, Cn);
  k_rope_split<<<Tn * Hn / 4, 256, 0, stream>>>(qkv_bf, cosT, sinT, q_r, k_r, v_s);
  k_attn<0><<<dim3(Tn / BR, Hn), 256, 0, stream>>>(q_r, k_r, v_s, nullptr, nullptr, pv1, dtl, kap, xiu);
  k_attn<1><<<dim3(Tn / BR, Hn), 256, 0, stream>>>(q_r, k_r, pv1, v_s, pv1, y_bf, dtl, kap, xiu);
  k_gemm_bt<1><<<dim3(Cn / 128, Tn / 128), 256, 0, stream>>>(y_bf, WprojT, out, Tn, Cn, Cn);
}

// Round 2
// 115.125 us; speedup vs baseline: 4.2236x; 4.2236x over previous
//
#include <hip/hip_runtime.h>
#include <hip/hip_bf16.h>

#define Tn 4096
#define Cn 768
#define Hn 12
#define DHn 64
#define BAND 192
#define QBLK 64
#define TJ 256        // BAND + QBLK staged keys per block
#define NTW 13        // 16-key tiles per wave (band window)

typedef __attribute__((ext_vector_type(8))) short short8;
typedef __attribute__((ext_vector_type(4))) short short4v;
typedef __attribute__((ext_vector_type(4))) float f32x4;

__device__ __forceinline__ float b2f(unsigned short u) {
  union { unsigned int i; float f; } z; z.i = ((unsigned int)u) << 16; return z.f;
}
__device__ __forceinline__ unsigned short f2b(float f) {
  union { float f; unsigned int i; } z; z.f = f;
  unsigned int r = z.i + 0x7FFFu + ((z.i >> 16) & 1u);
  return (unsigned short)(r >> 16);
}

// ---------------- f32 -> bf16 convert (vectorized) ----------------
__global__ __launch_bounds__(256) void k_f32_to_bf16(const float* __restrict__ in,
                                                     unsigned short* __restrict__ out, int n4) {
  int idx = blockIdx.x * 256 + threadIdx.x;
  int stride = gridDim.x * 256;
  for (int i = idx; i < n4; i += stride) {
    float4 v = ((const float4*)in)[i];
    short4v o;
    o.x = (short)f2b(v.x); o.y = (short)f2b(v.y);
    o.z = (short)f2b(v.z); o.w = (short)f2b(v.w);
    ((short4v*)out)[i] = o;
  }
}

// ---------------- W[K][N] f32 -> WT[N][K] bf16 (tiled transpose) ----------------
__global__ __launch_bounds__(256) void k_transpose_bf16(const float* __restrict__ W,
                                                        unsigned short* __restrict__ WT,
                                                        int K, int N) {
  __shared__ float tile[32][33];
  int n0 = blockIdx.x * 32, k0 = blockIdx.y * 32;
  int tx = threadIdx.x, ty = threadIdx.y; // 32 x 8
  for (int r = ty; r < 32; r += 8) tile[r][tx] = W[(size_t)(k0 + r) * N + n0 + tx];
  __syncthreads();
  for (int r = ty; r < 32; r += 8) WT[(size_t)(n0 + r) * K + k0 + tx] = f2b(tile[tx][r]);
}

// ---------------- bf16 MFMA GEMM: C[M,N] = A[M,K] * BT[N,K]^T ----------------
template<int EPI>
__global__ __launch_bounds__(256) void k_gemm_bt(const unsigned short* __restrict__ A,
                                                 const unsigned short* __restrict__ BT,
                                                 void* __restrict__ Cout,
                                                 int M, int N, int K) {
  __shared__ unsigned short As[128 * 32];
  __shared__ unsigned short Bs[128 * 32];
  int tid = threadIdx.x, lane = tid & 63, wave = tid >> 6;
  int wr = wave >> 1, wc = wave & 1;
  int m0 = blockIdx.y * 128, n0 = blockIdx.x * 128;
  f32x4 acc[4][4] = {};
  const unsigned short* Ab = A + (size_t)m0 * K;
  const unsigned short* Bb = BT + (size_t)n0 * K;
  int arow = (lane >> 2), acol = (lane & 3) * 8;
  for (int k0 = 0; k0 < K; k0 += 32) {
    __syncthreads();
#pragma unroll
    for (int u = 0; u < 2; ++u) {
      int s = wave * 2 + u;
      const unsigned short* ga = Ab + (size_t)(s * 16 + arow) * K + k0 + acol;
      const unsigned short* gb = Bb + (size_t)(s * 16 + arow) * K + k0 + acol;
      __builtin_amdgcn_global_load_lds((const __attribute__((address_space(1))) void*)ga,
                                       (__attribute__((address_space(3))) void*)(As + s * 512),
                                       16, 0, 0);
      __builtin_amdgcn_global_load_lds((const __attribute__((address_space(1))) void*)gb,
                                       (__attribute__((address_space(3))) void*)(Bs + s * 512),
                                       16, 0, 0);
    }
    __syncthreads();
    short8 a[4], b[4];
#pragma unroll
    for (int m = 0; m < 4; ++m)
      a[m] = *(const short8*)(As + (wr * 64 + m * 16 + (lane & 15)) * 32 + (lane >> 4) * 8);
#pragma unroll
    for (int n = 0; n < 4; ++n)
      b[n] = *(const short8*)(Bs + (wc * 64 + n * 16 + (lane & 15)) * 32 + (lane >> 4) * 8);
#pragma unroll
    for (int m = 0; m < 4; ++m)
#pragma unroll
      for (int n = 0; n < 4; ++n)
        acc[m][n] = __builtin_amdgcn_mfma_f32_16x16x32_bf16(a[m], b[n], acc[m][n], 0, 0, 0);
  }
  int r0 = m0 + wr * 64 + (lane >> 4) * 4;
  int c0 = n0 + wc * 64 + (lane & 15);
#pragma unroll
  for (int m = 0; m < 4; ++m)
#pragma unroll
    for (int n = 0; n < 4; ++n)
#pragma unroll
      for (int i = 0; i < 4; ++i) {
        int row = r0 + m * 16 + i, col = c0 + n * 16;
        if (EPI == 0) ((unsigned short*)Cout)[(size_t)row * N + col] = f2b(acc[m][n][i]);
        else          ((float*)Cout)[(size_t)row * N + col] = acc[m][n][i];
      }
}

// ---------------- RoPE + split heads ----------------
__global__ __launch_bounds__(256) void k_rope_split(const unsigned short* __restrict__ qkv,
                                                    const float* __restrict__ cosT,
                                                    const float* __restrict__ sinT,
                                                    unsigned short* __restrict__ qr,
                                                    unsigned short* __restrict__ kr,
                                                    unsigned short* __restrict__ vs) {
  int unit = blockIdx.x * 4 + (threadIdx.x >> 6);
  int lane = threadIdx.x & 63;
  int t = unit / Hn, h = unit % Hn;
  size_t base = (size_t)t * (3 * Cn);
  float cv = cosT[t * DHn + lane], sv = sinT[t * DHn + lane];
  float qv = b2f(qkv[base + h * DHn + lane]);
  float kv = b2f(qkv[base + Cn + h * DHn + lane]);
  unsigned short vv = qkv[base + 2 * Cn + h * DHn + lane];
  float sgn = (lane < 32) ? -1.f : 1.f;
  float qp = __shfl_xor(qv, 32);
  float kp = __shfl_xor(kv, 32);
  float qo = qv * cv + sgn * qp * sv;
  float ko = kv * cv + sgn * kp * sv;
  size_t o = ((size_t)h * Tn + t) * DHn + lane;
  qr[o] = f2b(qo); kr[o] = f2b(ko); vs[o] = vv;
}

// ---------------- banded causal attention, MFMA version ----------------
// PASS==0: out = P @ vin   ([H][T][64] bf16, unnormalized-P folded via 1/sum)
// PASS==1: out = y[T][C] = w0*v0 + w1*pv1 + w2*(P @ vin)
template<int PASS>
__global__ __launch_bounds__(256) void k_attn2(const unsigned short* __restrict__ qr,
                                               const unsigned short* __restrict__ kr,
                                               const unsigned short* __restrict__ vin,
                                               const unsigned short* __restrict__ v0,
                                               const unsigned short* __restrict__ pv1g,
                                               unsigned short* __restrict__ outp,
                                               const float* __restrict__ dt_logit_p,
                                               const float* __restrict__ kap_p,
                                               const float* __restrict__ xi_p) {
  __shared__ unsigned short Ks[TJ * DHn];   // row-major [256][64], 16B-unit XOR swizzle per row
  __shared__ unsigned short Vt[DHn * TJ];   // transposed [64][256], 16B-unit XOR swizzle per row
  int tid = threadIdx.x, lane = tid & 63, wave = tid >> 6;
  int lq = lane & 15, g = lane >> 4;
  int i0 = blockIdx.x * QBLK, h = blockIdx.y;
  int jt0 = i0 - BAND;
  const size_t headoff = (size_t)h * Tn * DHn;

  // ---- stage K via global_load_lds, source pre-swizzled so swizzled read is linear
  const unsigned short* krh = kr + headoff;
#pragma unroll
  for (int it = 0; it < 8; ++it) {
    int u = it * 256 + tid;
    int row = u >> 3, c8 = u & 7;
    int j = jt0 + row; j = j < 0 ? 0 : j;        // clamped rows masked later (j<0 mask)
    const unsigned short* ga = krh + (size_t)j * DHn + ((c8 ^ (row & 7)) << 3);
    __builtin_amdgcn_global_load_lds((const __attribute__((address_space(1))) void*)ga,
                                     (__attribute__((address_space(3))) void*)((char*)Ks + (size_t)(it * 256 + wave * 64) * 16),
                                     16, 0, 0);
  }

  // ---- Q fragments straight from global (each wave: 16 rows x 64 dh)
  const unsigned short* qrh = qr + headoff;
  int q0 = i0 + wave * 16;
  short8 qf0 = *(const short8*)(qrh + (size_t)(q0 + lq) * DHn + g * 8);
  short8 qf1 = *(const short8*)(qrh + (size_t)(q0 + lq) * DHn + 32 + g * 8);

  // ---- stage V transposed: Vt[d][k], swizzled rows
  {
    int j = jt0 + tid; j = j < 0 ? 0 : j;
    const unsigned short* vrow = vin + headoff + (size_t)j * DHn;
#pragma unroll
    for (int u = 0; u < 8; ++u) {
      short8 v8 = *(const short8*)(vrow + u * 8);
#pragma unroll
      for (int e = 0; e < 8; ++e) {
        int d = u * 8 + e;
        *(unsigned short*)((char*)Vt + d * 512 + ((tid * 2) ^ ((d & 7) << 4))) = (unsigned short)v8[e];
      }
    }
  }
  __syncthreads();

  // ---- S^T = K . Q^T over this wave's 13 key tiles (tiles wave..wave+12)
  f32x4 st[NTW];
#pragma unroll
  for (int t = 0; t < NTW; ++t) st[t] = (f32x4){0.f, 0.f, 0.f, 0.f};
#pragma unroll
  for (int t = 0; t < NTW; ++t) {
    int row = (wave + t) * 16 + lq;
    const char* kb = (const char*)Ks + row * 128;
    int sw = row & 7;
    short8 ka0 = *(const short8*)(kb + ((g ^ sw) << 4));
    short8 ka1 = *(const short8*)(kb + (((4 + g) ^ sw) << 4));
    st[t] = __builtin_amdgcn_mfma_f32_16x16x32_bf16(ka0, qf0, st[t], 0, 0, 0);
    st[t] = __builtin_amdgcn_mfma_f32_16x16x32_bf16(ka1, qf1, st[t], 0, 0, 0);
  }

  // ---- softmax (log2 domain), lane-local + 2 shfl_xor
  float kap = log1pf(__expf(*kap_p));
  float xi  = log1pf(__expf(*xi_p));
  const float LOG2E = 1.4426950408889634f;
  float sc = 0.125f * LOG2E;              // 1/sqrt(64) * log2(e)
  float c2 = kap / (xi * xi) * LOG2E;
  float db0 = (float)(lq + BAND - 4 * g);           // dist = db0 - 16t - r
  float jb0 = (float)(jt0 + 16 * wave + 4 * g);     // j    = jb0 + 16t + r
  float m = -3.0e38f;
#pragma unroll
  for (int t = 0; t < NTW; ++t) {
#pragma unroll
    for (int r = 0; r < 4; ++r) {
      float off = (float)(16 * t + r);
      float dist = db0 - off;
      float jv = jb0 + off;
      float l2 = fmaf(dist * dist, -c2, st[t][r] * sc);
      bool bad = (dist < 0.f) || (jv < 0.f);
      l2 = bad ? -3.0e38f : l2;
      st[t][r] = l2;
      m = fmaxf(m, l2);
    }
  }
  m = fmaxf(m, __shfl_xor(m, 16));
  m = fmaxf(m, __shfl_xor(m, 32));
  float sum = 0.f;
#pragma unroll
  for (int t = 0; t < NTW; ++t) {
#pragma unroll
    for (int r = 0; r < 4; ++r) {
      float p = exp2f(st[t][r] - m);
      st[t][r] = p;
      sum += p;
    }
  }
  sum += __shfl_xor(sum, 16);
  sum += __shfl_xor(sum, 32);

  // ---- pack P to bf16 pairs (per tile: regs 0,1 and 2,3)
  unsigned int pk0[NTW], pk1[NTW];
#pragma unroll
  for (int t = 0; t < NTW; ++t) {
    pk0[t] = (unsigned int)f2b(st[t][0]) | ((unsigned int)f2b(st[t][1]) << 16);
    pk1[t] = (unsigned int)f2b(st[t][2]) | ((unsigned int)f2b(st[t][3]) << 16);
  }

  // ---- PV: redistribute P into A-fragments via shfl, V B-fragments from Vt
  f32x4 oacc[4];
#pragma unroll
  for (int dt = 0; dt < 4; ++dt) oacc[dt] = (f32x4){0.f, 0.f, 0.f, 0.f};
  int srcA = lq + (g & 1) * 32;       // group 2*(g&1)
  int srcB = srcA + 16;               // group 2*(g&1)+1
  bool hiT = (g >= 2);
#pragma unroll
  for (int e = 0; e < 7; ++e) {
    unsigned int aA0 = __shfl(pk0[2 * e], srcA);
    unsigned int aA1 = __shfl(pk1[2 * e], srcA);
    unsigned int aB0 = __shfl(pk0[2 * e], srcB);
    unsigned int aB1 = __shfl(pk1[2 * e], srcB);
    unsigned int dw0, dw1, dw2, dw3;
    if (e < 6) {
      unsigned int bA0 = __shfl(pk0[2 * e + 1], srcA);
      unsigned int bA1 = __shfl(pk1[2 * e + 1], srcA);
      unsigned int bB0 = __shfl(pk0[2 * e + 1], srcB);
      unsigned int bB1 = __shfl(pk1[2 * e + 1], srcB);
      dw0 = hiT ? bA0 : aA0; dw1 = hiT ? bA1 : aA1;
      dw2 = hiT ? bB0 : aB0; dw3 = hiT ? bB1 : aB1;
    } else {
      dw0 = hiT ? 0u : aA0; dw1 = hiT ? 0u : aA1;
      dw2 = hiT ? 0u : aB0; dw3 = hiT ? 0u : aB1;
    }
    union { unsigned int u[4]; short8 s; } af;
    af.u[0] = dw0; af.u[1] = dw1; af.u[2] = dw2; af.u[3] = dw3;
    int k0 = 16 * wave + 32 * e + 8 * g;    // key base for this lane's B-frag elements
    if (k0 > TJ - 8) k0 = TJ - 8;           // stay in-bounds; those lanes have p==0
#pragma unroll
    for (int dt = 0; dt < 4; ++dt) {
      int d = dt * 16 + lq;
      short8 vb = *(const short8*)((char*)Vt + d * 512 + ((k0 * 2) ^ ((d & 7) << 4)));
      oacc[dt] = __builtin_amdgcn_mfma_f32_16x16x32_bf16(af.s, vb, oacc[dt], 0, 0, 0);
    }
  }

  // ---- epilogue: fold 1/sum; O row = 4g+r within wave's 16 queries, col = 16dt+lq
  float inv_s = 1.f / sum;
  float invq[4];
#pragma unroll
  for (int r = 0; r < 4; ++r) invq[r] = __shfl(inv_s, 4 * g + r);

  if (PASS == 0) {
#pragma unroll
    for (int dt = 0; dt < 4; ++dt)
#pragma unroll
      for (int r = 0; r < 4; ++r) {
        int i = i0 + 16 * wave + 4 * g + r;
        outp[headoff + (size_t)i * DHn + dt * 16 + lq] = f2b(oacc[dt][r] * invq[r]);
      }
  } else {
    float dtv = 1.f / (1.f + __expf(-*dt_logit_p));
    float a1 = dtv, a2 = 0.5f * dtv * dtv;
    float inv3 = 1.f / (1.f + a1 + a2);
    float w0 = inv3, w1 = a1 * inv3, w2 = a2 * inv3;
#pragma unroll
    for (int dt = 0; dt < 4; ++dt)
#pragma unroll
      for (int r = 0; r < 4; ++r) {
        int i = i0 + 16 * wave + 4 * g + r;
        size_t oidx = headoff + (size_t)i * DHn + dt * 16 + lq;
        float vv = b2f(v0[oidx]);
        float p1 = b2f(pv1g[oidx]);
        float yv = w0 * vv + w1 * p1 + w2 * (oacc[dt][r] * invq[r]);
        outp[(size_t)i * Cn + h * DHn + dt * 16 + lq] = f2b(yv);
      }
  }
}

extern "C" void kernel_launch(void* const* d_in, const int* in_sizes, int n_in,
                              void* d_out, int out_size, void* d_ws, size_t ws_size,
                              hipStream_t stream) {
  (void)in_sizes; (void)n_in; (void)out_size; (void)ws_size;
  const float* x     = (const float*)d_in[0];
  const float* cosT  = (const float*)d_in[1];
  const float* sinT  = (const float*)d_in[2];
  const float* Wqkv  = (const float*)d_in[3];
  const float* Wproj = (const float*)d_in[4];
  const float* dtl   = (const float*)d_in[5];
  const float* kap   = (const float*)d_in[6];
  const float* xiu   = (const float*)d_in[7];
  float* out = (float*)d_out;
  char* ws = (char*)d_ws;
  size_t off = 0;
  auto alloc = [&](size_t bytes) { char* p = ws + off; off += (bytes + 255) & ~(size_t)255; return p; };
  unsigned short* x_bf   = (unsigned short*)alloc((size_t)Tn * Cn * 2);
  unsigned short* WqkvT  = (unsigned short*)alloc((size_t)3 * Cn * Cn * 2);
  unsigned short* WprojT = (unsigned short*)alloc((size_t)Cn * Cn * 2);
  unsigned short* qkv_bf = (unsigned short*)alloc((size_t)Tn * 3 * Cn * 2);
  unsigned short* q_r    = (unsigned short*)alloc((size_t)Hn * Tn * DHn * 2);
  unsigned short* k_r    = (unsigned short*)alloc((size_t)Hn * Tn * DHn * 2);
  unsigned short* v_s    = (unsigned short*)alloc((size_t)Hn * Tn * DHn * 2);
  unsigned short* pv1    = (unsigned short*)alloc((size_t)Hn * Tn * DHn * 2);
  unsigned short* y_bf   = (unsigned short*)alloc((size_t)Tn * Cn * 2);

  k_f32_to_bf16<<<512, 256, 0, stream>>>(x, x_bf, Tn * Cn / 4);
  k_transpose_bf16<<<dim3(3 * Cn / 32, Cn / 32), dim3(32, 8), 0, stream>>>(Wqkv, WqkvT, Cn, 3 * Cn);
  k_transpose_bf16<<<dim3(Cn / 32, Cn / 32), dim3(32, 8), 0, stream>>>(Wproj, WprojT, Cn, Cn);
  k_gemm_bt<0><<<dim3(3 * Cn / 128, Tn / 128), 256, 0, stream>>>(x_bf, WqkvT, qkv_bf, Tn, 3 * Cn, Cn);
  k_rope_split<<<Tn * Hn / 4, 256, 0, stream>>>(qkv_bf, cosT, sinT, q_r, k_r, v_s);
  k_attn2<0><<<dim3(Tn / QBLK, Hn), 256, 0, stream>>>(q_r, k_r, v_s, nullptr, nullptr, pv1, dtl, kap, xiu);
  k_attn2<1><<<dim3(Tn / QBLK, Hn), 256, 0, stream>>>(q_r, k_r, pv1, v_s, pv1, y_bf, dtl, kap, xiu);
  k_gemm_bt<1><<<dim3(Cn / 128, Tn / 128), 256, 0, stream>>>(y_bf, WprojT, out, Tn, Cn, Cn);
}

// Round 3
// 107.698 us; speedup vs baseline: 4.5149x; 1.0690x over previous
//
#include <hip/hip_runtime.h>
#include <hip/hip_bf16.h>

#define Tn 4096
#define Cn 768
#define Hn 12
#define DHn 64
#define BAND 192
#define QBLK 64
#define TJ 256        // BAND + QBLK staged keys per block
#define NTW 13        // 16-key tiles per wave (band window)

typedef __attribute__((ext_vector_type(8))) short short8;
typedef __attribute__((ext_vector_type(4))) short short4v;
typedef __attribute__((ext_vector_type(4))) float f32x4;

__device__ __forceinline__ float b2f(unsigned short u) {
  union { unsigned int i; float f; } z; z.i = ((unsigned int)u) << 16; return z.f;
}
__device__ __forceinline__ unsigned short f2b(float f) {
  union { float f; unsigned int i; } z; z.f = f;
  unsigned int r = z.i + 0x7FFFu + ((z.i >> 16) & 1u);
  return (unsigned short)(r >> 16);
}

// ---------------- f32 -> bf16 convert (vectorized) ----------------
__global__ __launch_bounds__(256) void k_f32_to_bf16(const float* __restrict__ in,
                                                     unsigned short* __restrict__ out, int n4) {
  int idx = blockIdx.x * 256 + threadIdx.x;
  int stride = gridDim.x * 256;
  for (int i = idx; i < n4; i += stride) {
    float4 v = ((const float4*)in)[i];
    short4v o;
    o.x = (short)f2b(v.x); o.y = (short)f2b(v.y);
    o.z = (short)f2b(v.z); o.w = (short)f2b(v.w);
    ((short4v*)out)[i] = o;
  }
}

// ---------------- W[K][N] f32 -> WT[N][K] bf16 (tiled transpose) ----------------
__global__ __launch_bounds__(256) void k_transpose_bf16(const float* __restrict__ W,
                                                        unsigned short* __restrict__ WT,
                                                        int K, int N) {
  __shared__ float tile[32][33];
  int n0 = blockIdx.x * 32, k0 = blockIdx.y * 32;
  int tx = threadIdx.x, ty = threadIdx.y; // 32 x 8
  for (int r = ty; r < 32; r += 8) tile[r][tx] = W[(size_t)(k0 + r) * N + n0 + tx];
  __syncthreads();
  for (int r = ty; r < 32; r += 8) WT[(size_t)(n0 + r) * K + k0 + tx] = f2b(tile[tx][r]);
}

// ---------------- bf16 MFMA GEMM: C[M,N] = A[M,K] * BT[N,K]^T ----------------
template<int EPI>
__global__ __launch_bounds__(256) void k_gemm_bt(const unsigned short* __restrict__ A,
                                                 const unsigned short* __restrict__ BT,
                                                 void* __restrict__ Cout,
                                                 int M, int N, int K) {
  __shared__ unsigned short As[128 * 32];
  __shared__ unsigned short Bs[128 * 32];
  int tid = threadIdx.x, lane = tid & 63, wave = tid >> 6;
  int wr = wave >> 1, wc = wave & 1;
  int m0 = blockIdx.y * 128, n0 = blockIdx.x * 128;
  f32x4 acc[4][4] = {};
  const unsigned short* Ab = A + (size_t)m0 * K;
  const unsigned short* Bb = BT + (size_t)n0 * K;
  int arow = (lane >> 2), acol = (lane & 3) * 8;
  for (int k0 = 0; k0 < K; k0 += 32) {
    __syncthreads();
#pragma unroll
    for (int u = 0; u < 2; ++u) {
      int s = wave * 2 + u;
      const unsigned short* ga = Ab + (size_t)(s * 16 + arow) * K + k0 + acol;
      const unsigned short* gb = Bb + (size_t)(s * 16 + arow) * K + k0 + acol;
      __builtin_amdgcn_global_load_lds((const __attribute__((address_space(1))) void*)ga,
                                       (__attribute__((address_space(3))) void*)(As + s * 512),
                                       16, 0, 0);
      __builtin_amdgcn_global_load_lds((const __attribute__((address_space(1))) void*)gb,
                                       (__attribute__((address_space(3))) void*)(Bs + s * 512),
                                       16, 0, 0);
    }
    __syncthreads();
    short8 a[4], b[4];
#pragma unroll
    for (int m = 0; m < 4; ++m)
      a[m] = *(const short8*)(As + (wr * 64 + m * 16 + (lane & 15)) * 32 + (lane >> 4) * 8);
#pragma unroll
    for (int n = 0; n < 4; ++n)
      b[n] = *(const short8*)(Bs + (wc * 64 + n * 16 + (lane & 15)) * 32 + (lane >> 4) * 8);
#pragma unroll
    for (int m = 0; m < 4; ++m)
#pragma unroll
      for (int n = 0; n < 4; ++n)
        acc[m][n] = __builtin_amdgcn_mfma_f32_16x16x32_bf16(a[m], b[n], acc[m][n], 0, 0, 0);
  }
  int r0 = m0 + wr * 64 + (lane >> 4) * 4;
  int c0 = n0 + wc * 64 + (lane & 15);
#pragma unroll
  for (int m = 0; m < 4; ++m)
#pragma unroll
    for (int n = 0; n < 4; ++n)
#pragma unroll
      for (int i = 0; i < 4; ++i) {
        int row = r0 + m * 16 + i, col = c0 + n * 16;
        if (EPI == 0) ((unsigned short*)Cout)[(size_t)row * N + col] = f2b(acc[m][n][i]);
        else          ((float*)Cout)[(size_t)row * N + col] = acc[m][n][i];
      }
}

// ---------------- RoPE + split heads ----------------
__global__ __launch_bounds__(256) void k_rope_split(const unsigned short* __restrict__ qkv,
                                                    const float* __restrict__ cosT,
                                                    const float* __restrict__ sinT,
                                                    unsigned short* __restrict__ qr,
                                                    unsigned short* __restrict__ kr,
                                                    unsigned short* __restrict__ vs) {
  int unit = blockIdx.x * 4 + (threadIdx.x >> 6);
  int lane = threadIdx.x & 63;
  int t = unit / Hn, h = unit % Hn;
  size_t base = (size_t)t * (3 * Cn);
  float cv = cosT[t * DHn + lane], sv = sinT[t * DHn + lane];
  float qv = b2f(qkv[base + h * DHn + lane]);
  float kv = b2f(qkv[base + Cn + h * DHn + lane]);
  unsigned short vv = qkv[base + 2 * Cn + h * DHn + lane];
  float sgn = (lane < 32) ? -1.f : 1.f;
  float qp = __shfl_xor(qv, 32);
  float kp = __shfl_xor(kv, 32);
  float qo = qv * cv + sgn * qp * sv;
  float ko = kv * cv + sgn * kp * sv;
  size_t o = ((size_t)h * Tn + t) * DHn + lane;
  qr[o] = f2b(qo); kr[o] = f2b(ko); vs[o] = vv;
}

// ---- stage a 256x64 bf16 tile into LDS in 4x16-subtiled layout via global_load_lds ----
// LDS layout: addr(j,d) = (j>>2)*512 + (d>>4)*128 + (j&3)*32 + (d&15)*2   (bytes)
__device__ __forceinline__ void stage_subtiled(const unsigned short* __restrict__ srcHead,
                                               int jt0, unsigned short* lds, int tid, int wave) {
#pragma unroll
  for (int it = 0; it < 8; ++it) {
    int c = it * 256 + tid;                       // 16B chunk index
    int j = jt0 + ((c >> 5) << 2) + ((c & 7) >> 1);
    j = j < 0 ? 0 : j;
    int d0 = (((c >> 3) & 3) << 4) + ((c & 1) << 3);
    const unsigned short* ga = srcHead + (size_t)j * DHn + d0;
    __builtin_amdgcn_global_load_lds((const __attribute__((address_space(1))) void*)ga,
                                     (__attribute__((address_space(3))) void*)(lds + (it * 4 + wave) * 512),
                                     16, 0, 0);
  }
}

// ---- PV: 7 A-frags (P) x subtiled-V tile -> oacc[4] via ds_read_b64_tr_b16 ----
__device__ __forceinline__ void pv_tr(const unsigned short* Vt, const short8* af,
                                      int wave, int lane, f32x4* oacc) {
  int lq = lane & 15, g = lane >> 4;
  unsigned base = (unsigned)(size_t)(const __attribute__((address_space(3))) unsigned short*)Vt;
  unsigned pl = base + lq * 8;
#pragma unroll
  for (int e = 0; e < 7; ++e) {
    int kl = 16 * wave + 32 * e + 8 * g;
    if (kl > TJ - 8) kl = TJ - 8;          // those lanes carry p==0
    unsigned pe = pl + kl * 128;
    unsigned long long rr[8];
#pragma unroll
    for (int dt = 0; dt < 4; ++dt) {
      asm volatile("ds_read_b64_tr_b16 %0, %1" : "=v"(rr[2 * dt]) : "v"(pe + dt * 128));
      asm volatile("ds_read_b64_tr_b16 %0, %1" : "=v"(rr[2 * dt + 1]) : "v"(pe + dt * 128 + 512));
    }
    asm volatile("s_waitcnt lgkmcnt(0)");
    __builtin_amdgcn_sched_barrier(0);
#pragma unroll
    for (int dt = 0; dt < 4; ++dt) {
      union { unsigned long long u[2]; short8 s; } vb;
      vb.u[0] = rr[2 * dt]; vb.u[1] = rr[2 * dt + 1];
      oacc[dt] = __builtin_amdgcn_mfma_f32_16x16x32_bf16(af[e], vb.s, oacc[dt], 0, 0, 0);
    }
  }
}

// ---------------- pass A: QK^T + softmax; write pv1 and normalized P fragments ----------------
__global__ __launch_bounds__(256) void k_attn_a(const unsigned short* __restrict__ qr,
                                                const unsigned short* __restrict__ kr,
                                                const unsigned short* __restrict__ vin,
                                                unsigned short* __restrict__ pv1out,
                                                unsigned short* __restrict__ pfrag,
                                                const float* __restrict__ kap_p,
                                                const float* __restrict__ xi_p) {
  __shared__ unsigned short Ks[TJ * DHn];   // row-major, 16B-unit XOR swizzle per row
  __shared__ unsigned short Vt[TJ * DHn];   // 4x16 subtiled for tr_read
  int tid = threadIdx.x, lane = tid & 63, wave = tid >> 6;
  int lq = lane & 15, g = lane >> 4;
  int i0 = blockIdx.x * QBLK, h = blockIdx.y;
  int jt0 = i0 - BAND;
  const size_t headoff = (size_t)h * Tn * DHn;

  // stage K (swizzled rows, pre-swizzled global source)
  const unsigned short* krh = kr + headoff;
#pragma unroll
  for (int it = 0; it < 8; ++it) {
    int u = it * 256 + tid;
    int row = u >> 3, c8 = u & 7;
    int j = jt0 + row; j = j < 0 ? 0 : j;
    const unsigned short* ga = krh + (size_t)j * DHn + ((c8 ^ (row & 7)) << 3);
    __builtin_amdgcn_global_load_lds((const __attribute__((address_space(1))) void*)ga,
                                     (__attribute__((address_space(3))) void*)((char*)Ks + (size_t)(it * 256 + wave * 64) * 16),
                                     16, 0, 0);
  }
  // stage V subtiled
  stage_subtiled(vin + headoff, jt0, Vt, tid, wave);

  // Q fragments from global
  const unsigned short* qrh = qr + headoff;
  int q0 = i0 + wave * 16;
  short8 qf0 = *(const short8*)(qrh + (size_t)(q0 + lq) * DHn + g * 8);
  short8 qf1 = *(const short8*)(qrh + (size_t)(q0 + lq) * DHn + 32 + g * 8);
  __syncthreads();

  // S^T = K . Q^T over this wave's 13 key tiles
  f32x4 st[NTW];
#pragma unroll
  for (int t = 0; t < NTW; ++t) st[t] = (f32x4){0.f, 0.f, 0.f, 0.f};
#pragma unroll
  for (int t = 0; t < NTW; ++t) {
    int row = (wave + t) * 16 + lq;
    const char* kb = (const char*)Ks + row * 128;
    int sw = row & 7;
    short8 ka0 = *(const short8*)(kb + ((g ^ sw) << 4));
    short8 ka1 = *(const short8*)(kb + (((4 + g) ^ sw) << 4));
    st[t] = __builtin_amdgcn_mfma_f32_16x16x32_bf16(ka0, qf0, st[t], 0, 0, 0);
    st[t] = __builtin_amdgcn_mfma_f32_16x16x32_bf16(ka1, qf1, st[t], 0, 0, 0);
  }

  // softmax (log2 domain), lane-local + 2 shfl_xor
  float kap = log1pf(__expf(*kap_p));
  float xi  = log1pf(__expf(*xi_p));
  const float LOG2E = 1.4426950408889634f;
  float sc = 0.125f * LOG2E;
  float c2 = kap / (xi * xi) * LOG2E;
  float db0 = (float)(lq + BAND - 4 * g);
  float jb0 = (float)(jt0 + 16 * wave + 4 * g);
  float m = -3.0e38f;
#pragma unroll
  for (int t = 0; t < NTW; ++t) {
#pragma unroll
    for (int r = 0; r < 4; ++r) {
      float off = (float)(16 * t + r);
      float dist = db0 - off;
      float jv = jb0 + off;
      float l2 = fmaf(dist * dist, -c2, st[t][r] * sc);
      bool bad = (dist < 0.f) || (jv < 0.f);
      l2 = bad ? -3.0e38f : l2;
      st[t][r] = l2;
      m = fmaxf(m, l2);
    }
  }
  m = fmaxf(m, __shfl_xor(m, 16));
  m = fmaxf(m, __shfl_xor(m, 32));
  float sum = 0.f;
#pragma unroll
  for (int t = 0; t < NTW; ++t) {
#pragma unroll
    for (int r = 0; r < 4; ++r) {
      float p = exp2f(st[t][r] - m);
      st[t][r] = p;
      sum += p;
    }
  }
  sum += __shfl_xor(sum, 16);
  sum += __shfl_xor(sum, 32);
  float inv_s = 1.f / sum;

  // pack NORMALIZED P to bf16 pairs
  unsigned int pk0[NTW], pk1[NTW];
#pragma unroll
  for (int t = 0; t < NTW; ++t) {
    pk0[t] = (unsigned int)f2b(st[t][0] * inv_s) | ((unsigned int)f2b(st[t][1] * inv_s) << 16);
    pk1[t] = (unsigned int)f2b(st[t][2] * inv_s) | ((unsigned int)f2b(st[t][3] * inv_s) << 16);
  }

  // redistribute into A-fragments via shfl
  short8 af[7];
  int srcA = lq + (g & 1) * 32;
  int srcB = srcA + 16;
  bool hiT = (g >= 2);
#pragma unroll
  for (int e = 0; e < 7; ++e) {
    unsigned int aA0 = __shfl(pk0[2 * e], srcA);
    unsigned int aA1 = __shfl(pk1[2 * e], srcA);
    unsigned int aB0 = __shfl(pk0[2 * e], srcB);
    unsigned int aB1 = __shfl(pk1[2 * e], srcB);
    unsigned int dw0, dw1, dw2, dw3;
    if (e < 6) {
      unsigned int bA0 = __shfl(pk0[2 * e + 1], srcA);
      unsigned int bA1 = __shfl(pk1[2 * e + 1], srcA);
      unsigned int bB0 = __shfl(pk0[2 * e + 1], srcB);
      unsigned int bB1 = __shfl(pk1[2 * e + 1], srcB);
      dw0 = hiT ? bA0 : aA0; dw1 = hiT ? bA1 : aA1;
      dw2 = hiT ? bB0 : aB0; dw3 = hiT ? bB1 : aB1;
    } else {
      dw0 = hiT ? 0u : aA0; dw1 = hiT ? 0u : aA1;
      dw2 = hiT ? 0u : aB0; dw3 = hiT ? 0u : aB1;
    }
    union { unsigned int u[4]; short8 s; } t2;
    t2.u[0] = dw0; t2.u[1] = dw1; t2.u[2] = dw2; t2.u[3] = dw3;
    af[e] = t2.s;
  }

  // store P fragments (coalesced 16B/lane)
  size_t pfb = ((((size_t)h * (Tn / QBLK) + blockIdx.x) * 4 + wave) * 7) * 512 + (size_t)lane * 8;
#pragma unroll
  for (int e = 0; e < 7; ++e)
    *(short8*)(pfrag + pfb + (size_t)e * 512) = af[e];

  // PV via tr_read
  f32x4 oacc[4];
#pragma unroll
  for (int dt = 0; dt < 4; ++dt) oacc[dt] = (f32x4){0.f, 0.f, 0.f, 0.f};
  pv_tr(Vt, af, wave, lane, oacc);

  // epilogue: row = 4g+r within wave's 16 queries, col = 16dt+lq (already normalized)
#pragma unroll
  for (int dt = 0; dt < 4; ++dt)
#pragma unroll
    for (int r = 0; r < 4; ++r) {
      int i = i0 + 16 * wave + 4 * g + r;
      pv1out[headoff + (size_t)i * DHn + dt * 16 + lq] = f2b(oacc[dt][r]);
    }
}

// ---------------- pass B: pv2 = P @ pv1 (P from stored frags); combine -> y[T][C] ----------------
__global__ __launch_bounds__(256) void k_attn_b(const unsigned short* __restrict__ pv1,
                                                const unsigned short* __restrict__ v0,
                                                const unsigned short* __restrict__ pfrag,
                                                unsigned short* __restrict__ yout,
                                                const float* __restrict__ dt_logit_p) {
  __shared__ unsigned short Vt[TJ * DHn];   // subtiled pv1 tile
  int tid = threadIdx.x, lane = tid & 63, wave = tid >> 6;
  int lq = lane & 15, g = lane >> 4;
  int i0 = blockIdx.x * QBLK, h = blockIdx.y;
  int jt0 = i0 - BAND;
  const size_t headoff = (size_t)h * Tn * DHn;

  stage_subtiled(pv1 + headoff, jt0, Vt, tid, wave);

  // load P fragments
  short8 af[7];
  size_t pfb = ((((size_t)h * (Tn / QBLK) + blockIdx.x) * 4 + wave) * 7) * 512 + (size_t)lane * 8;
#pragma unroll
  for (int e = 0; e < 7; ++e)
    af[e] = *(const short8*)(pfrag + pfb + (size_t)e * 512);
  __syncthreads();

  f32x4 oacc[4];
#pragma unroll
  for (int dt = 0; dt < 4; ++dt) oacc[dt] = (f32x4){0.f, 0.f, 0.f, 0.f};
  pv_tr(Vt, af, wave, lane, oacc);

  float dtv = 1.f / (1.f + __expf(-*dt_logit_p));
  float a1 = dtv, a2 = 0.5f * dtv * dtv;
  float inv3 = 1.f / (1.f + a1 + a2);
  float w0 = inv3, w1 = a1 * inv3, w2 = a2 * inv3;

#pragma unroll
  for (int dt = 0; dt < 4; ++dt)
#pragma unroll
    for (int r = 0; r < 4; ++r) {
      int i = i0 + 16 * wave + 4 * g + r;
      // pv1[i][d] from the staged subtiled tile (row 192 + i-i0)
      int j = 192 + 16 * wave + 4 * g + r;
      unsigned boff = (unsigned)((j >> 2) * 512 + dt * 128 + (j & 3) * 32 + lq * 2);
      float p1 = b2f(*(const unsigned short*)((const char*)Vt + boff));
      float vv = b2f(v0[headoff + (size_t)i * DHn + dt * 16 + lq]);
      float yv = w0 * vv + w1 * p1 + w2 * oacc[dt][r];
      yout[(size_t)i * Cn + h * DHn + dt * 16 + lq] = f2b(yv);
    }
}

extern "C" void kernel_launch(void* const* d_in, const int* in_sizes, int n_in,
                              void* d_out, int out_size, void* d_ws, size_t ws_size,
                              hipStream_t stream) {
  (void)in_sizes; (void)n_in; (void)out_size; (void)ws_size;
  const float* x     = (const float*)d_in[0];
  const float* cosT  = (const float*)d_in[1];
  const float* sinT  = (const float*)d_in[2];
  const float* Wqkv  = (const float*)d_in[3];
  const float* Wproj = (const float*)d_in[4];
  const float* dtl   = (const float*)d_in[5];
  const float* kap   = (const float*)d_in[6];
  const float* xiu   = (const float*)d_in[7];
  float* out = (float*)d_out;
  char* ws = (char*)d_ws;
  size_t off = 0;
  auto alloc = [&](size_t bytes) { char* p = ws + off; off += (bytes + 255) & ~(size_t)255; return p; };
  unsigned short* x_bf   = (unsigned short*)alloc((size_t)Tn * Cn * 2);
  unsigned short* WqkvT  = (unsigned short*)alloc((size_t)3 * Cn * Cn * 2);
  unsigned short* WprojT = (unsigned short*)alloc((size_t)Cn * Cn * 2);
  unsigned short* qkv_bf = (unsigned short*)alloc((size_t)Tn * 3 * Cn * 2);
  unsigned short* q_r    = (unsigned short*)alloc((size_t)Hn * Tn * DHn * 2);
  unsigned short* k_r    = (unsigned short*)alloc((size_t)Hn * Tn * DHn * 2);
  unsigned short* v_s    = (unsigned short*)alloc((size_t)Hn * Tn * DHn * 2);
  unsigned short* pv1    = (unsigned short*)alloc((size_t)Hn * Tn * DHn * 2);
  unsigned short* y_bf   = (unsigned short*)alloc((size_t)Tn * Cn * 2);
  unsigned short* pfrag  = (unsigned short*)alloc((size_t)Hn * (Tn / QBLK) * 4 * 7 * 512 * 2);

  k_f32_to_bf16<<<512, 256, 0, stream>>>(x, x_bf, Tn * Cn / 4);
  k_transpose_bf16<<<dim3(3 * Cn / 32, Cn / 32), dim3(32, 8), 0, stream>>>(Wqkv, WqkvT, Cn, 3 * Cn);
  k_transpose_bf16<<<dim3(Cn / 32, Cn / 32), dim3(32, 8), 0, stream>>>(Wproj, WprojT, Cn, Cn);
  k_gemm_bt<0><<<dim3(3 * Cn / 128, Tn / 128), 256, 0, stream>>>(x_bf, WqkvT, qkv_bf, Tn, 3 * Cn, Cn);
  k_rope_split<<<Tn * Hn / 4, 256, 0, stream>>>(qkv_bf, cosT, sinT, q_r, k_r, v_s);
  k_attn_a<<<dim3(Tn / QBLK, Hn), 256, 0, stream>>>(q_r, k_r, v_s, pv1, pfrag, kap, xiu);
  k_attn_b<<<dim3(Tn / QBLK, Hn), 256, 0, stream>>>(pv1, v_s, pfrag, y_bf, dtl);
  k_gemm_bt<1><<<dim3(Cn / 128, Tn / 128), 256, 0, stream>>>(y_bf, WprojT, out, Tn, Cn, Cn);
}